// Round 14
// baseline (276.261 us; speedup 1.0000x reference)
//
#include <hip/hip_runtime.h>

#define THREADS 256
#define BIGT 1024             // wide blocks for latency-bound passes
#define NBLK 256              // blocks for bin passes (private-region radix)
#define BSHIFT 8              // 256 dst-nodes per bucket
#define BSZ (1 << BSHIFT)
#define MAXB 512              // max buckets (N <= 131072)
#define MAXSB 128             // max scan chunks (T <= 131072)

// Per-block dtype probe: sample this block's edge range; int64 layout => odd words
// (high words of values < 2^31) are all zero. Words 2i+1, i < E, are in-bounds for
// both layouts (int32 buffer has 2E words). 1024 random samples => P(false int64) ~ 0.
__device__ __forceinline__ bool probe_int64(const void* ei, int s, int e, int tid, int* nz) {
    if (tid == 0) *nz = 0;
    __syncthreads();
    int i = s + tid;
    if (i < e && ((const unsigned int*)ei)[2 * i + 1] != 0u) atomicOr(nz, 1);
    __syncthreads();
    return (*nz == 0);
}

// ---------- pass 1: per-block bucket histogram over dst (reads raw edge_index) ----------
__global__ __launch_bounds__(BIGT) void bin_count_kernel(
        const void* __restrict__ ei, int* __restrict__ blockhist, int E, int NB) {
    __shared__ int h[MAXB];
    __shared__ int nz;
    int tid = threadIdx.x;
    for (int i = tid; i < NB; i += blockDim.x) h[i] = 0;
    int chunk = (E + gridDim.x - 1) / gridDim.x;
    int s = blockIdx.x * chunk;
    int e = min(E, s + chunk);
    bool is64 = probe_int64(ei, s, e, tid, &nz);   // syncs cover h zero-init too
    if (is64) {
        const long long* p = (const long long*)ei;
        for (int i = s + tid; i < e; i += blockDim.x)
            atomicAdd(&h[(int)p[E + i] >> BSHIFT], 1);
    } else {
        const int* p = (const int*)ei;
        for (int i = s + tid; i < e; i += blockDim.x)
            atomicAdd(&h[p[E + i] >> BSHIFT], 1);
    }
    __syncthreads();
    for (int i = tid; i < NB; i += blockDim.x)
        blockhist[i * NBLK + blockIdx.x] = h[i];   // bucket-major for scan
}

// ---------- scan: per-1024-chunk local exclusive scan + chunk totals ----------
// (consumers re-scan the <=128 partials in LDS and add the chunk prefix themselves)
__global__ void scan_blocks_kernel(const int* __restrict__ cnt, int* __restrict__ ofs,
                                   int* __restrict__ partials, int T) {
    __shared__ int sd[THREADS];
    int tid = threadIdx.x;
    int base = blockIdx.x * 1024 + tid * 4;
    int c0 = (base + 0 < T) ? cnt[base + 0] : 0;
    int c1 = (base + 1 < T) ? cnt[base + 1] : 0;
    int c2 = (base + 2 < T) ? cnt[base + 2] : 0;
    int c3 = (base + 3 < T) ? cnt[base + 3] : 0;
    int tsum = c0 + c1 + c2 + c3;
    sd[tid] = tsum;
    __syncthreads();
    for (int off = 1; off < THREADS; off <<= 1) {
        int t = (tid >= off) ? sd[tid - off] : 0;
        __syncthreads();
        sd[tid] += t;
        __syncthreads();
    }
    int excl = sd[tid] - tsum;
    if (base + 0 < T) ofs[base + 0] = excl;
    if (base + 1 < T) ofs[base + 1] = excl + c0;
    if (base + 2 < T) ofs[base + 2] = excl + c0 + c1;
    if (base + 3 < T) ofs[base + 3] = excl + c0 + c1 + c2;
    if (tid == THREADS - 1) partials[blockIdx.x] = sd[tid];
}

// in-LDS inclusive scan of chunk partials; returns via pscan[]; pscan[c-1] = excl prefix of chunk c
__device__ __forceinline__ void scan_partials_lds(const int* __restrict__ partials,
                                                  int* pscan, int tid, int SB) {
    if (tid < MAXSB) pscan[tid] = (tid < SB) ? partials[tid] : 0;
    __syncthreads();
    for (int off = 1; off < MAXSB; off <<= 1) {
        int t = (tid < MAXSB && tid >= off) ? pscan[tid - off] : 0;
        __syncthreads();
        if (tid < MAXSB) pscan[tid] += t;
        __syncthreads();
    }
}

// ---------- pass 2: write edges into private (bucket, block) regions; no global atomics ----------
__global__ __launch_bounds__(BIGT) void bin_write_kernel(
        const void* __restrict__ ei, const int* __restrict__ ofs_local,
        const int* __restrict__ partials, unsigned int* __restrict__ ebuf,
        int E, int NB, int SB) {
    __shared__ int cur[MAXB];
    __shared__ int pscan[MAXSB];
    __shared__ int nz;
    int tid = threadIdx.x;
    scan_partials_lds(partials, pscan, tid, SB);
    for (int i = tid; i < NB; i += blockDim.x) {
        int idx = i * NBLK + blockIdx.x;
        int c = idx >> 10;
        cur[i] = ((c > 0) ? pscan[c - 1] : 0) + ofs_local[idx];
    }
    int chunk = (E + gridDim.x - 1) / gridDim.x;
    int s = blockIdx.x * chunk;
    int e = min(E, s + chunk);
    bool is64 = probe_int64(ei, s, e, tid, &nz);   // syncs also publish cur[]
    if (is64) {
        const long long* p = (const long long*)ei;
        for (int i = s + tid; i < e; i += blockDim.x) {
            int d = (int)p[E + i];
            int sr = (int)p[i];
            int pos = atomicAdd(&cur[d >> BSHIFT], 1);   // LDS cursor -> private region
            ebuf[pos] = ((unsigned int)(d & (BSZ - 1)) << 20) | (unsigned int)sr;  // src < 2^20
        }
    } else {
        const int* p = (const int*)ei;
        for (int i = s + tid; i < e; i += blockDim.x) {
            int d = p[E + i];
            int sr = p[i];
            int pos = atomicAdd(&cur[d >> BSHIFT], 1);
            ebuf[pos] = ((unsigned int)(d & (BSZ - 1)) << 20) | (unsigned int)sr;
        }
    }
}

// ---------- fused per-bucket: degree/rowptr/dinv + col placement + dense1 ----------
__global__ __launch_bounds__(BIGT) void place_dense_kernel(
        const unsigned int* __restrict__ ebuf, const int* __restrict__ ofs_local,
        const int* __restrict__ partials,
        const float* __restrict__ x, const float* __restrict__ W1,
        int* __restrict__ rowptr, float* __restrict__ dinv, int* __restrict__ col,
        float* __restrict__ ht1, int N, int NB, int SB, int E) {
    __shared__ int cnt[BSZ];
    __shared__ int scanbuf[BSZ];
    __shared__ int baseL[BSZ];
    __shared__ int fillL[BSZ];
    __shared__ float dinvL[BSZ];
    __shared__ float Wt[1024];    // Wt[k*32+j] = W1[j*32+k]
    __shared__ float xs[BIGT];
    __shared__ int pscan[MAXSB];
    int b = blockIdx.x;
    int lo = b << BSHIFT;
    int tid = threadIdx.x;
    if (tid < BSZ) cnt[tid] = 0;
    Wt[(tid & 31) * 32 + (tid >> 5)] = W1[tid];   // BIGT == 1024 covers all
    scan_partials_lds(partials, pscan, tid, SB);  // syncs cover cnt/Wt init
    int i0 = b * NBLK;
    int start = ((i0 >> 10) > 0 ? pscan[(i0 >> 10) - 1] : 0) + ofs_local[i0];
    int end;
    if (b == NB - 1) end = E;
    else {
        int i1 = (b + 1) * NBLK;
        end = ((i1 >> 10) > 0 ? pscan[(i1 >> 10) - 1] : 0) + ofs_local[i1];
    }
    // pass A: per-node degree count (ebuf region ~32KB, L2-resident)
    for (int p = start + tid; p < end; p += BIGT)
        atomicAdd(&cnt[(ebuf[p] >> 20) & (BSZ - 1)], 1);
    __syncthreads();
    // exclusive scan of cnt (only tid<BSZ touch LDS)
    int c = (tid < BSZ) ? cnt[tid] : 0;
    if (tid < BSZ) scanbuf[tid] = c;
    __syncthreads();
    for (int off = 1; off < BSZ; off <<= 1) {
        int t = (tid < BSZ && tid >= off) ? scanbuf[tid - off] : 0;
        __syncthreads();
        if (tid < BSZ) scanbuf[tid] += t;
        __syncthreads();
    }
    if (tid < BSZ) {
        int excl = scanbuf[tid] - c;
        int node = lo + tid;
        float dv = 1.0f / sqrtf((float)(c + 1));   // +1 self loop
        dinvL[tid] = dv;
        if (node < N) {
            rowptr[node] = start + excl;
            dinv[node] = dv;
            if (node == N - 1) rowptr[N] = start + excl + c;   // == E
        }
        baseL[tid] = start + excl;
        fillL[tid] = 0;
    }
    __syncthreads();
    // pass B: place (col writes confined to this bucket's ~50KB window; ebuf re-read is L2-hit)
    for (int p = start + tid; p < end; p += BIGT) {
        unsigned int v = ebuf[p];
        int dl = (v >> 20) & (BSZ - 1);
        int pos = baseL[dl] + atomicAdd(&fillL[dl], 1);
        col[pos] = (int)(v & 0xFFFFFu);
    }
    __syncthreads();
    // dense1: ht1[n] = (x[n] @ W1^T) * dinv[n]  for this bucket's 256 nodes
    for (int base0 = 0; base0 < BSZ * 32; base0 += BIGT) {
        int idx = base0 + tid;            // 0..8191
        int ln = idx >> 5;                // local node
        int node = lo + ln;
        xs[tid] = (node < N) ? x[(size_t)lo * 32 + idx] : 0.f;
        __syncthreads();
        if (node < N) {
            int j = idx & 31;
            const float* xr = xs + ((tid >> 5) << 5);
            float s = 0.f;
#pragma unroll
            for (int k = 0; k < 32; ++k) s = fmaf(xr[k], Wt[k * 32 + j], s);
            ht1[(size_t)node * 32 + j] = s * dinvL[ln];
        }
        __syncthreads();
    }
}

// ---------- fused agg1 + dense2: ht2 = ((relu(dinv*(gather)+b1)) @ W2^T) * dinv ----------
// unroll-16 gather: 16 independent loads in flight (transient regs, W stays in LDS)
__global__ __launch_bounds__(THREADS) void agg_dense_kernel(
        const float* __restrict__ ht1, const int* __restrict__ rowptr,
        const int* __restrict__ col, const float* __restrict__ dinv,
        const float* __restrict__ b1, const float* __restrict__ W2,
        float* __restrict__ ht2, int N) {
    __shared__ float Wt[1024];    // Wt[k*32+j] = W2[j*32+k]
    __shared__ float hr[THREADS]; // 8 node-rows of h1
    int tid = threadIdx.x;
    for (int idx = tid; idx < 1024; idx += THREADS)
        Wt[(idx & 31) * 32 + (idx >> 5)] = W2[idx];
    int gid = blockIdx.x * THREADS + tid;
    int n = gid >> 5;
    int j = gid & 31;
    bool act = (n < N);
    float h1v = 0.f, dv = 0.f;
    if (act) {
        dv = dinv[n];
        float s = ht1[gid];               // self loop
        int p = rowptr[n], end = rowptr[n + 1];
        for (; p + 16 <= end; p += 16) {
            int cc[16];
            float vv[16];
#pragma unroll
            for (int u = 0; u < 16; ++u) cc[u] = col[p + u];
#pragma unroll
            for (int u = 0; u < 16; ++u) vv[u] = ht1[cc[u] * 32 + j];
            s += (((vv[0] + vv[1]) + (vv[2] + vv[3])) + ((vv[4] + vv[5]) + (vv[6] + vv[7])))
               + (((vv[8] + vv[9]) + (vv[10] + vv[11])) + ((vv[12] + vv[13]) + (vv[14] + vv[15])));
        }
        for (; p + 4 <= end; p += 4) {
            int c0 = col[p], c1 = col[p + 1], c2 = col[p + 2], c3 = col[p + 3];
            float v0 = ht1[c0 * 32 + j];
            float v1 = ht1[c1 * 32 + j];
            float v2 = ht1[c2 * 32 + j];
            float v3 = ht1[c3 * 32 + j];
            s += (v0 + v1) + (v2 + v3);
        }
        for (; p < end; ++p) s += ht1[col[p] * 32 + j];
        h1v = fmaxf(fmaf(dv, s, b1[j]), 0.f);
    }
    hr[tid] = h1v;
    __syncthreads();                       // also covers Wt load
    if (act) {
        const float* hrow = hr + ((tid >> 5) << 5);
        float t = 0.f;
#pragma unroll
        for (int k = 0; k < 32; ++k) t = fmaf(hrow[k], Wt[k * 32 + j], t);
        ht2[gid] = t * dv;
    }
}

// ---------- final aggregate: out = relu(dinv * (self + gather) + b2) ----------
__global__ __launch_bounds__(THREADS) void agg_final_kernel(
        const float* __restrict__ ht2, const int* __restrict__ rowptr,
        const int* __restrict__ col, const float* __restrict__ dinv,
        const float* __restrict__ bias, float* __restrict__ out, int N) {
    int gid = blockIdx.x * THREADS + threadIdx.x;
    int n = gid >> 5;
    if (n >= N) return;
    int j = gid & 31;
    float s = ht2[gid];
    int p = rowptr[n], end = rowptr[n + 1];
    for (; p + 16 <= end; p += 16) {
        int cc[16];
        float vv[16];
#pragma unroll
        for (int u = 0; u < 16; ++u) cc[u] = col[p + u];
#pragma unroll
        for (int u = 0; u < 16; ++u) vv[u] = ht2[cc[u] * 32 + j];
        s += (((vv[0] + vv[1]) + (vv[2] + vv[3])) + ((vv[4] + vv[5]) + (vv[6] + vv[7])))
           + (((vv[8] + vv[9]) + (vv[10] + vv[11])) + ((vv[12] + vv[13]) + (vv[14] + vv[15])));
    }
    for (; p + 4 <= end; p += 4) {
        int c0 = col[p], c1 = col[p + 1], c2 = col[p + 2], c3 = col[p + 3];
        float v0 = ht2[c0 * 32 + j];
        float v1 = ht2[c1 * 32 + j];
        float v2 = ht2[c2 * 32 + j];
        float v3 = ht2[c3 * 32 + j];
        s += (v0 + v1) + (v2 + v3);
    }
    for (; p < end; ++p) s += ht2[col[p] * 32 + j];
    float r = fmaxf(fmaf(dinv[n], s, bias[j]), 0.f);
    __builtin_nontemporal_store(r, out + gid);   // output never re-read
}

extern "C" void kernel_launch(void* const* d_in, const int* in_sizes, int n_in,
                              void* d_out, int out_size, void* d_ws, size_t ws_size,
                              hipStream_t stream) {
    const float* x  = (const float*)d_in[0];
    const void*  ei = d_in[1];
    const float* W1 = (const float*)d_in[2];
    const float* b1 = (const float*)d_in[3];
    const float* W2 = (const float*)d_in[4];
    const float* b2 = (const float*)d_in[5];
    float* out = (float*)d_out;

    int N = in_sizes[0] / 32;
    long long twoE = (long long)in_sizes[1];
    int E = (int)(twoE / 2);
    int NB = (N + BSZ - 1) >> BSHIFT;          // buckets (391 for N=100000)
    int T  = NB * NBLK;                        // blockhist entries (100096)
    int SB = (T + 1023) / 1024;                // scan chunks (98 <= 128)

    char* ws = (char*)d_ws;
    size_t o = 0;
    auto alloc = [&](size_t bytes) { size_t r = o; o += (bytes + 255) & ~(size_t)255; return r; };
    int*   blockhist = (int*)(ws + alloc((size_t)T * 4));
    int*   ofs_local = (int*)(ws + alloc((size_t)T * 4));
    int*   rowptr    = (int*)(ws + alloc((size_t)(N + 1) * 4));
    int*   partials  = (int*)(ws + alloc(512));
    float* dinv      = (float*)(ws + alloc((size_t)N * 4));
    unsigned int* ebuf = (unsigned int*)(ws + alloc((size_t)E * 4));
    int*   col       = (int*)(ws + alloc((size_t)E * 4));
    float* ht1       = (float*)(ws + alloc((size_t)N * 32 * 4));
    float* ht2       = (float*)(ws + alloc((size_t)N * 32 * 4));

    bin_count_kernel<<<NBLK, BIGT, 0, stream>>>(ei, blockhist, E, NB);
    scan_blocks_kernel<<<SB, THREADS, 0, stream>>>(blockhist, ofs_local, partials, T);
    bin_write_kernel<<<NBLK, BIGT, 0, stream>>>(ei, ofs_local, partials, ebuf, E, NB, SB);
    place_dense_kernel<<<NB, BIGT, 0, stream>>>(ebuf, ofs_local, partials, x, W1,
                                                rowptr, dinv, col, ht1, N, NB, SB, E);

    int GB = (N * 32 + THREADS - 1) / THREADS;
    agg_dense_kernel<<<GB, THREADS, 0, stream>>>(ht1, rowptr, col, dinv, b1, W2, ht2, N);
    agg_final_kernel<<<GB, THREADS, 0, stream>>>(ht2, rowptr, col, dinv, b2, out, N);
}